// Round 13
// baseline (633.357 us; speedup 1.0000x reference)
//
#include <hip/hip_runtime.h>
#include <hip/hip_bf16.h>

// GraphSAGE 3-layer, N=100000, E=1600000, 128->128->16, f32.
// R11 (2nd resubmit; GPU-acquisition timeouts, never ran):
//   fuse agg+BN+ReLU with the NEXT layer's GEMM. Block b aggregates its own
//   64 nodes (Phase A) straight into the swizzled LDS bf16 hi/lo tiles, then
//   runs the proven MFMA body (Phase B). Kills the h round-trip (2x ~100MB
//   L2/L3 traffic) and 2 kernel boundaries. s buffer updated in-place per-row
//   (each block reads only its own rows before overwriting). 6 launches.

constexpr int N   = 100000;
constexpr int E   = 1600000;
constexpr int F   = 128;
constexpr int FO  = 16;
constexpr int CAP = 64;   // max in-degree; Poisson(16)

constexpr int GEMM_BLOCKS = (N + 63) / 64;        // 1563 = 521*3
constexpr int FILL_BLOCKS = 1042;                 // 521*2
constexpr int FUSED_GRID  = GEMM_BLOCKS + FILL_BLOCKS;  // 2605

typedef __attribute__((ext_vector_type(8))) short bf16x8;
typedef __attribute__((ext_vector_type(4))) float f32x4;

__device__ __forceinline__ ushort f2bf(float v) {
  return __bfloat16_as_ushort(__float2bfloat16(v));
}
__device__ __forceinline__ float bf2f(ushort u) {
  return __uint_as_float(((unsigned)u) << 16);
}
__device__ __forceinline__ float bf_lo(unsigned u) {
  return __uint_as_float(u << 16);
}
__device__ __forceinline__ float bf_hi(unsigned u) {
  return __uint_as_float(u & 0xffff0000u);
}

// ------------- weight prepack: Bt0,Bt1 [256][128], Bt2 [32][128] -------------
__global__ void pack3_k(const float* __restrict__ Wn0, const float* __restrict__ Ws0,
                        const float* __restrict__ Wn1, const float* __restrict__ Ws1,
                        const float* __restrict__ Wn2, const float* __restrict__ Ws2,
                        ushort* __restrict__ Bt0, ushort* __restrict__ Bt1,
                        ushort* __restrict__ Bt2) {
  int t = blockIdx.x * blockDim.x + threadIdx.x;
  if (t < 65536) {
    int which = t >> 15;
    int i = t & 32767;
    int n = i >> 7, k = i & 127;
    const float* Wn = which ? Wn1 : Wn0;
    const float* Ws = which ? Ws1 : Ws0;
    float w = (n < 128) ? Wn[k * F + n] : Ws[k * F + (n - 128)];
    (which ? Bt1 : Bt0)[i] = f2bf(w);
  } else if (t < 65536 + 4096) {
    int i = t - 65536;
    int n = i >> 7, k = i & 127;
    float w = (n < FO) ? Wn2[k * FO + n] : Ws2[k * FO + (n - FO)];
    Bt2[i] = f2bf(w);
  }
}

// ------------- 4-stream gather-mean of bf16 rows (verbatim R10 inner loop) ---
__device__ __forceinline__ void gather_mean(
    const int* __restrict__ sl, int deg, const ushort* __restrict__ ybuf,
    int c2, float& mlo, float& mhi) {
  float a0 = 0.f, a1 = 0.f, a2 = 0.f, a3 = 0.f;
  float b0 = 0.f, b1 = 0.f, b2 = 0.f, b3 = 0.f;
  int e = 0;
  for (; e + 4 <= deg; e += 4) {
    int n0 = sl[e], n1 = sl[e + 1], n2 = sl[e + 2], n3 = sl[e + 3];
    unsigned u0 = *reinterpret_cast<const unsigned*>(ybuf + (size_t)n0 * F + c2 * 2);
    unsigned u1 = *reinterpret_cast<const unsigned*>(ybuf + (size_t)n1 * F + c2 * 2);
    unsigned u2 = *reinterpret_cast<const unsigned*>(ybuf + (size_t)n2 * F + c2 * 2);
    unsigned u3 = *reinterpret_cast<const unsigned*>(ybuf + (size_t)n3 * F + c2 * 2);
    a0 += bf_lo(u0); b0 += bf_hi(u0);
    a1 += bf_lo(u1); b1 += bf_hi(u1);
    a2 += bf_lo(u2); b2 += bf_hi(u2);
    a3 += bf_lo(u3); b3 += bf_hi(u3);
  }
  for (; e < deg; ++e) {
    unsigned u = *reinterpret_cast<const unsigned*>(ybuf + (size_t)sl[e] * F + c2 * 2);
    a0 += bf_lo(u); b0 += bf_hi(u);
  }
  const float inv = 1.0f / fmaxf((float)deg, 1.0f);
  mlo = ((a0 + a1) + (a2 + a3)) * inv;
  mhi = ((b0 + b1) + (b2 + b3)) * inv;
}

// ------------- MFMA dual GEMM body (R10, unchanged): needs staged Ahi/Alo ----
__device__ __forceinline__ void gemm_stage_from_global(
    int row0, int tid, const float* __restrict__ h_in, char* Ahi, char* Alo) {
#pragma unroll
  for (int j = 0; j < 4; ++j) {
    int f = tid + j * 256;
    int row = f >> 4;
    int kc = f & 15;
    int gr = row0 + row; if (gr >= N) gr = N - 1;
    const float4* gp = reinterpret_cast<const float4*>(h_in + (size_t)gr * F + kc * 8);
    float4 v0 = gp[0], v1 = gp[1];
    float vv[8] = {v0.x, v0.y, v0.z, v0.w, v1.x, v1.y, v1.z, v1.w};
    unsigned ph[4], pl[4];
#pragma unroll
    for (int q = 0; q < 4; ++q) {
      ushort h0 = f2bf(vv[2 * q]);
      ushort h1 = f2bf(vv[2 * q + 1]);
      ushort l0 = f2bf(vv[2 * q] - bf2f(h0));
      ushort l1 = f2bf(vv[2 * q + 1] - bf2f(h1));
      ph[q] = (unsigned)h0 | ((unsigned)h1 << 16);
      pl[q] = (unsigned)l0 | ((unsigned)l1 << 16);
    }
    int off = (row * 256 + kc * 16) ^ ((row & 7) << 4);
    *reinterpret_cast<uint4*>(Ahi + off) = make_uint4(ph[0], ph[1], ph[2], ph[3]);
    *reinterpret_cast<uint4*>(Alo + off) = make_uint4(pl[0], pl[1], pl[2], pl[3]);
  }
}

__device__ __forceinline__ void gemm_mfma_256(
    int row0, int tid, const ushort* __restrict__ Bt, const float* __restrict__ b,
    ushort* __restrict__ y, float* __restrict__ s, char* Ahi, char* Alo) {
  const int lane = tid & 63;
  const int wave = tid >> 6;
  const int wcol0 = wave * 64;
  const int lg = lane >> 4;
  const int lr = lane & 15;

  f32x4 acc[4][4];
#pragma unroll
  for (int r = 0; r < 4; ++r)
#pragma unroll
    for (int c = 0; c < 4; ++c) acc[r][c] = f32x4{0.f, 0.f, 0.f, 0.f};

#pragma unroll
  for (int kk = 0; kk < 4; ++kk) {
    bf16x8 bfr[4];
#pragma unroll
    for (int c = 0; c < 4; ++c) {
      int col = wcol0 + c * 16 + lr;
      bfr[c] = *reinterpret_cast<const bf16x8*>(Bt + (size_t)col * F + kk * 32 + lg * 8);
    }
#pragma unroll
    for (int r = 0; r < 4; ++r) {
      int row = r * 16 + lr;
      int off = (row * 256 + kk * 64 + lg * 16) ^ ((row & 7) << 4);
      bf16x8 a = *reinterpret_cast<const bf16x8*>(Ahi + off);
#pragma unroll
      for (int c = 0; c < 4; ++c)
        acc[r][c] = __builtin_amdgcn_mfma_f32_16x16x32_bf16(a, bfr[c], acc[r][c], 0, 0, 0);
    }
#pragma unroll
    for (int r = 0; r < 4; ++r) {
      int row = r * 16 + lr;
      int off = (row * 256 + kk * 64 + lg * 16) ^ ((row & 7) << 4);
      bf16x8 a = *reinterpret_cast<const bf16x8*>(Alo + off);
#pragma unroll
      for (int c = 0; c < 4; ++c)
        acc[r][c] = __builtin_amdgcn_mfma_f32_16x16x32_bf16(a, bfr[c], acc[r][c], 0, 0, 0);
    }
  }

  if (wave < 2) {
#pragma unroll
    for (int r = 0; r < 4; ++r)
#pragma unroll
      for (int c = 0; c < 4; ++c) {
        int col = wcol0 + c * 16 + lr;
#pragma unroll
        for (int q = 0; q < 4; ++q) {
          int grow = row0 + r * 16 + lg * 4 + q;
          if (grow < N) y[(size_t)grow * F + col] = f2bf(acc[r][c][q]);
        }
      }
  } else {
#pragma unroll
    for (int r = 0; r < 4; ++r)
#pragma unroll
      for (int c = 0; c < 4; ++c) {
        int scol = wcol0 - 128 + c * 16 + lr;
        float bias = b[scol];
#pragma unroll
        for (int q = 0; q < 4; ++q) {
          int grow = row0 + r * 16 + lg * 4 + q;
          if (grow < N) s[(size_t)grow * F + scol] = acc[r][c][q] + bias;
        }
      }
  }
}

// ------------- fused0: layer-0 dual GEMM + adjacency fill (R10) --------------
__global__ __launch_bounds__(256) void fused0_k(
    const float* __restrict__ x, const ushort* __restrict__ Bt0,
    const float* __restrict__ b0,
    ushort* __restrict__ y, float* __restrict__ s,
    const int* __restrict__ src, const int* __restrict__ dst,
    int* __restrict__ degc, int* __restrict__ slots) {
  __shared__ uint4 AsU[2048];
  char* Ahi = reinterpret_cast<char*>(AsU);
  char* Alo = Ahi + 64 * 256;
  const int gid = blockIdx.x;
  const int grp = gid / 5, rem = gid % 5;
  const int tid = threadIdx.x;

  if (rem < 3) {
    int bg = grp * 3 + rem;
    gemm_stage_from_global(bg * 64, tid, x, Ahi, Alo);
    __syncthreads();
    gemm_mfma_256(bg * 64, tid, Bt0, b0, y, s, Ahi, Alo);
  } else {
    const int bf = grp * 2 + (rem - 3);
    int i = bf * 256 + tid;
    const int stride = FILL_BLOCKS * 256;
    for (; i < E; i += stride) {
      int d = dst[i];
      int pos = atomicAdd(&degc[d], 1);
      if (pos < CAP)
        __builtin_nontemporal_store(src[i], &slots[(size_t)d * CAP + pos]);
    }
  }
}

// ------------- fused1: agg(y0)+BN0+ReLU -> LDS -> GEMM1 -> y1, s (in-place) --
__global__ __launch_bounds__(256) void fused1_k(
    const int* __restrict__ degc, const int* __restrict__ slots,
    const ushort* __restrict__ yA, float* __restrict__ s,
    const float* __restrict__ g, const float* __restrict__ be,
    const float* __restrict__ rm, const float* __restrict__ rv,
    const ushort* __restrict__ Bt1, const float* __restrict__ b1,
    ushort* __restrict__ yB) {
  __shared__ uint4 AsU[2048];
  char* Ahi = reinterpret_cast<char*>(AsU);
  char* Alo = Ahi + 64 * 256;
  const int tid = threadIdx.x;
  const int row0 = blockIdx.x * 64;
  const int nd = tid >> 6;
  const int c2 = tid & 63;
  const int cA = c2 * 2;

  float2 gv = *reinterpret_cast<const float2*>(g + cA);
  float2 bev = *reinterpret_cast<const float2*>(be + cA);
  float2 rmv = *reinterpret_cast<const float2*>(rm + cA);
  float2 rvv = *reinterpret_cast<const float2*>(rv + cA);
  const float sc0 = rsqrtf(rvv.x + 1e-5f) * gv.x;
  const float sc1 = rsqrtf(rvv.y + 1e-5f) * gv.y;

#pragma unroll 1
  for (int round = 0; round < 16; ++round) {
    int row = round * 4 + nd;
    int node = row0 + row;
    int nc = node < N ? node : N - 1;
    int deg = degc[nc]; if (deg > CAP) deg = CAP;
    float mlo, mhi;
    gather_mean(slots + (size_t)nc * CAP, deg, yA, c2, mlo, mhi);
    float2 sv = *reinterpret_cast<const float2*>(s + (size_t)nc * F + cA);
    float olo = fmaxf((mlo + sv.x - rmv.x) * sc0 + bev.x, 0.f);
    float ohi = fmaxf((mhi + sv.y - rmv.y) * sc1 + bev.y, 0.f);
    ushort h0 = f2bf(olo), l0 = f2bf(olo - bf2f(h0));
    ushort h1 = f2bf(ohi), l1 = f2bf(ohi - bf2f(h1));
    int off = (row * 256 + c2 * 4) ^ ((row & 7) << 4);
    *reinterpret_cast<unsigned*>(Ahi + off) = (unsigned)h0 | ((unsigned)h1 << 16);
    *reinterpret_cast<unsigned*>(Alo + off) = (unsigned)l0 | ((unsigned)l1 << 16);
  }
  __syncthreads();
  // s rows [row0,row0+64) were fully read above; safe to overwrite in-place.
  gemm_mfma_256(row0, tid, Bt1, b1, yB, s, Ahi, Alo);
}

// ------------- fused2: agg(y1)+BN1+ReLU -> LDS -> GEMM2(32 col) -> y2, s2 ----
__global__ __launch_bounds__(256) void fused2_k(
    const int* __restrict__ degc, const int* __restrict__ slots,
    const ushort* __restrict__ yB, const float* __restrict__ s,
    const float* __restrict__ g, const float* __restrict__ be,
    const float* __restrict__ rm, const float* __restrict__ rv,
    const ushort* __restrict__ Bt2, const float* __restrict__ b2,
    ushort* __restrict__ y2, float* __restrict__ s2) {
  __shared__ uint4 AsU[2048];
  char* Ahi = reinterpret_cast<char*>(AsU);
  char* Alo = Ahi + 64 * 256;
  const int tid = threadIdx.x;
  const int row0 = blockIdx.x * 64;
  const int nd = tid >> 6;
  const int c2 = tid & 63;
  const int cA = c2 * 2;

  float2 gv = *reinterpret_cast<const float2*>(g + cA);
  float2 bev = *reinterpret_cast<const float2*>(be + cA);
  float2 rmv = *reinterpret_cast<const float2*>(rm + cA);
  float2 rvv = *reinterpret_cast<const float2*>(rv + cA);
  const float sc0 = rsqrtf(rvv.x + 1e-5f) * gv.x;
  const float sc1 = rsqrtf(rvv.y + 1e-5f) * gv.y;

#pragma unroll 1
  for (int round = 0; round < 16; ++round) {
    int row = round * 4 + nd;
    int node = row0 + row;
    int nc = node < N ? node : N - 1;
    int deg = degc[nc]; if (deg > CAP) deg = CAP;
    float mlo, mhi;
    gather_mean(slots + (size_t)nc * CAP, deg, yB, c2, mlo, mhi);
    float2 sv = *reinterpret_cast<const float2*>(s + (size_t)nc * F + cA);
    float olo = fmaxf((mlo + sv.x - rmv.x) * sc0 + bev.x, 0.f);
    float ohi = fmaxf((mhi + sv.y - rmv.y) * sc1 + bev.y, 0.f);
    ushort h0 = f2bf(olo), l0 = f2bf(olo - bf2f(h0));
    ushort h1 = f2bf(ohi), l1 = f2bf(ohi - bf2f(h1));
    int off = (row * 256 + c2 * 4) ^ ((row & 7) << 4);
    *reinterpret_cast<unsigned*>(Ahi + off) = (unsigned)h0 | ((unsigned)h1 << 16);
    *reinterpret_cast<unsigned*>(Alo + off) = (unsigned)l0 | ((unsigned)l1 << 16);
  }
  __syncthreads();

  const int lane = tid & 63;
  const int wave = tid >> 6;
  if (wave >= 2) return;                   // 32 output cols need 2 waves only
  const int lg = lane >> 4;
  const int lr = lane & 15;
  const int col = wave * 16 + lr;          // 0..31 in Bt2

  f32x4 acc[4];
#pragma unroll
  for (int r = 0; r < 4; ++r) acc[r] = f32x4{0.f, 0.f, 0.f, 0.f};

#pragma unroll
  for (int kk = 0; kk < 4; ++kk) {
    bf16x8 bfr = *reinterpret_cast<const bf16x8*>(Bt2 + (size_t)col * F + kk * 32 + lg * 8);
#pragma unroll
    for (int r = 0; r < 4; ++r) {
      int row = r * 16 + lr;
      int off = (row * 256 + kk * 64 + lg * 16) ^ ((row & 7) << 4);
      bf16x8 a = *reinterpret_cast<const bf16x8*>(Ahi + off);
      acc[r] = __builtin_amdgcn_mfma_f32_16x16x32_bf16(a, bfr, acc[r], 0, 0, 0);
    }
#pragma unroll
    for (int r = 0; r < 4; ++r) {
      int row = r * 16 + lr;
      int off = (row * 256 + kk * 64 + lg * 16) ^ ((row & 7) << 4);
      bf16x8 a = *reinterpret_cast<const bf16x8*>(Alo + off);
      acc[r] = __builtin_amdgcn_mfma_f32_16x16x32_bf16(a, bfr, acc[r], 0, 0, 0);
    }
  }

  if (wave == 0) {                         // cols 0..15 -> y2 (bf16)
#pragma unroll
    for (int r = 0; r < 4; ++r)
#pragma unroll
      for (int q = 0; q < 4; ++q) {
        int grow = row0 + r * 16 + lg * 4 + q;
        if (grow < N) y2[(size_t)grow * FO + lr] = f2bf(acc[r][q]);
      }
  } else {                                 // cols 16..31 -> s2 (f32 + bias)
    float bias = b2[lr];
#pragma unroll
    for (int r = 0; r < 4; ++r)
#pragma unroll
      for (int q = 0; q < 4; ++q) {
        int grow = row0 + r * 16 + lg * 4 + q;
        if (grow < N) s2[(size_t)grow * FO + lr] = acc[r][q] + bias;
      }
  }
}

// ------------- output agg: out = mean_gather(y2) + s2 (unchanged) ------------
__global__ __launch_bounds__(256) void agg_out_k(
    const int* __restrict__ degc, const int* __restrict__ slots,
    const ushort* __restrict__ y2, const float* __restrict__ s2,
    float* __restrict__ out) {
  const int node = blockIdx.x * 4 + (threadIdx.x >> 6);
  const int lane = threadIdx.x & 63;
  const int c = lane & 15;
  const int j = lane >> 4;
  int deg = degc[node]; if (deg > CAP) deg = CAP;
  const int* sl = slots + (size_t)node * CAP;
  float acc = 0.f;
  for (int e = j; e < deg; e += 4) {
    unsigned bits = y2[(size_t)sl[e] * FO + c];
    acc += __uint_as_float(bits << 16);
  }
  acc += __shfl_xor(acc, 16, 64);
  acc += __shfl_xor(acc, 32, 64);
  if (j == 0)
    out[(size_t)node * FO + c] = acc / fmaxf((float)deg, 1.0f) + s2[(size_t)node * FO + c];
}

extern "C" void kernel_launch(void* const* d_in, const int* in_sizes, int n_in,
                              void* d_out, int out_size, void* d_ws, size_t ws_size,
                              hipStream_t stream) {
  const float* x   = (const float*)d_in[0];
  const int*   ei  = (const int*)d_in[1];
  const float* Wn0 = (const float*)d_in[2];
  const float* b0  = (const float*)d_in[3];
  const float* Ws0 = (const float*)d_in[4];
  const float* Wn1 = (const float*)d_in[5];
  const float* b1  = (const float*)d_in[6];
  const float* Ws1 = (const float*)d_in[7];
  const float* Wn2 = (const float*)d_in[8];
  const float* b2  = (const float*)d_in[9];
  const float* Ws2 = (const float*)d_in[10];
  const float* g0  = (const float*)d_in[11];
  const float* be0 = (const float*)d_in[12];
  const float* rm0 = (const float*)d_in[13];
  const float* rv0 = (const float*)d_in[14];
  const float* g1  = (const float*)d_in[15];
  const float* be1 = (const float*)d_in[16];
  const float* rm1 = (const float*)d_in[17];
  const float* rv1 = (const float*)d_in[18];

  const int* src = ei;       // edge_index[0]
  const int* dst = ei + E;   // edge_index[1]

  // ws layout (~128.6 MB, under proven 154):
  //   degc[N] int | slots[N*CAP] int | yA[N*F] bf16 | s[N*F] f32 (in-place
  //   L0->L1) | yB[N*F] bf16 | Bt0[32768] | Bt1[32768] | Bt2[4096] bf16
  //   y2[N*FO] bf16 + s2[N*FO] f32 alias the dead yA region in fused2.
  int* degc    = (int*)d_ws;
  int* slots   = degc + N;
  ushort* yA   = (ushort*)(slots + (size_t)N * CAP);
  float* s     = (float*)(yA + (size_t)N * F);
  ushort* yB   = (ushort*)(s + (size_t)N * F);
  ushort* Bt0  = yB + (size_t)N * F;
  ushort* Bt1  = Bt0 + 256 * 128;
  ushort* Bt2  = Bt1 + 256 * 128;
  ushort* y2   = yA;                                  // N*FO bf16 (3.2 MB)
  float*  s2   = (float*)(yA + (size_t)N * FO);       // N*FO f32 (6.4 MB)

  // ---- prepack weights + zero degree counters ----
  hipMemsetAsync(degc, 0, N * sizeof(int), stream);
  pack3_k<<<273, 256, 0, stream>>>(Wn0, Ws0, Wn1, Ws1, Wn2, Ws2, Bt0, Bt1, Bt2);

  // ---- layer 0 GEMM + adjacency fill (independent, overlapped) ----
  fused0_k<<<FUSED_GRID, 256, 0, stream>>>(x, Bt0, b0, yA, s, src, dst, degc, slots);

  // ---- layer 1: agg(y0)+BN+ReLU -> GEMM1 ----
  fused1_k<<<GEMM_BLOCKS, 256, 0, stream>>>(degc, slots, yA, s,
                                            g0, be0, rm0, rv0, Bt1, b1, yB);

  // ---- layer 2: agg(y1)+BN+ReLU -> GEMM2 ----
  fused2_k<<<GEMM_BLOCKS, 256, 0, stream>>>(degc, slots, yB, s,
                                            g1, be1, rm1, rv1, Bt2, b2, y2, s2);

  // ---- output aggregation ----
  agg_out_k<<<N / 4, 256, 0, stream>>>(degc, slots, y2, s2, (float*)d_out);
}